// Round 1
// baseline (21098.744 us; speedup 1.0000x reference)
//
#include <hip/hip_runtime.h>
#include <hip/hip_fp16.h>
#include <cstdint>
#include <cstddef>

#define EPSF 2.220446049250313e-16f

// Sizes (fixed by the problem)
#define Bn   64
#define TP2n 1024
#define Tn   1023
#define Hn   256
#define H7n  1792
#define Kn   128
#define Sn   1024
#define NEn  131

typedef _Float16 f16x2 __attribute__((ext_vector_type(2)));

__device__ __forceinline__ float fdot2f(f16x2 a, f16x2 b, float c) {
#if __has_builtin(__builtin_amdgcn_fdot2)
  return __builtin_amdgcn_fdot2(a, b, c, false);
#else
  return c + (float)a[0] * (float)b[0] + (float)a[1] * (float)b[1];
#endif
}

__device__ __forceinline__ float sigmf(float x) { return 1.f / (1.f + __expf(-x)); }

__device__ __forceinline__ float tanhfast(float x) {
  float t = __expf(2.f * fabsf(x));        // inf-safe: t=inf -> r=1
  float r = 1.f - 2.f / (t + 1.f);
  return copysignf(r, x);
}

__device__ __forceinline__ float softplusf(float x) {
  // stable: max(x,0) + log1p(exp(-|x|))
  return fmaxf(x, 0.f) + log1pf(__expf(-fabsf(x)));
}

// ---------------------------------------------------------------------------
// EW[e][r] = b[r] + sum_k Emb[e][k] * W[r][k]   (input half of W, k<256)
__global__ void k_ew(const float* __restrict__ Emb, const float* __restrict__ W,
                     const float* __restrict__ bvec, float* __restrict__ EW) {
  int e = blockIdx.x;  // 0..130
  __shared__ float es[Hn];
  for (int k = threadIdx.x; k < Hn; k += blockDim.x) es[k] = Emb[e * Hn + k];
  __syncthreads();
  for (int r = threadIdx.x; r < H7n; r += blockDim.x) {
    const float* wr = W + (size_t)r * (2 * Hn);
    float acc = bvec[r];
#pragma unroll 4
    for (int k = 0; k < Hn; ++k) acc += es[k] * wr[k];
    EW[e * H7n + r] = acc;
  }
}

// ---------------------------------------------------------------------------
// Recurrent weights, fp16, per-thread-contiguous layout:
// wt[r2*128 + k2] = { half2(W[2r2][256+2k2], W[2r2][256+2k2+1]),
//                     half2(W[2r2+1][256+2k2], W[2r2+1][256+2k2+1]) }
__global__ void k_wt(const float* __restrict__ W, uint2* __restrict__ wt) {
  int gid = blockIdx.x * blockDim.x + threadIdx.x;
  if (gid >= 896 * 128) return;
  int r2 = gid >> 7, k2 = gid & 127;
  const float* w0 = W + (size_t)(2 * r2) * 512 + 256 + 2 * k2;
  const float* w1 = w0 + 512;
  f16x2 a; a[0] = (_Float16)w0[0]; a[1] = (_Float16)w0[1];
  f16x2 b; b[0] = (_Float16)w1[0]; b[1] = (_Float16)w1[1];
  uint2 o;
  o.x = __builtin_bit_cast(unsigned, a);
  o.y = __builtin_bit_cast(unsigned, b);
  wt[(size_t)r2 * 128 + k2] = o;
}

// ---------------------------------------------------------------------------
__global__ void k_init(float* __restrict__ lam_acc, float* __restrict__ mask_acc) {
  int i = threadIdx.x;
  if (i < Bn) { lam_acc[i] = 0.f; mask_acc[i] = 0.f; }
}

// ---------------------------------------------------------------------------
// Sequential CT-LSTM scan. One block per batch; 896 threads; thread t owns
// z-rows 2t, 2t+1. Phase A: z = EW[e] + W_hh * h (fp16 dot2). Phase B
// (threads 0..255): gates, state update, fp16 state store, target-row
// log-lambda dot (deferred combine by thread 0, double-buffered partials).
__global__ __launch_bounds__(896) void k_scan(
    const int* __restrict__ event, const float* __restrict__ dtime,
    const float* __restrict__ EW, const uint2* __restrict__ wt,
    const float* __restrict__ Wl,
    __half* __restrict__ oc, __half* __restrict__ ocb,
    __half* __restrict__ ogd, __half* __restrict__ ogo,
    float* __restrict__ loglik_sum) {
  const int b = blockIdx.x;
  const int tid = threadIdx.x;

  __shared__ float  zbuf[H7n];
  __shared__ float  c_s[Hn], cb_s[Hn];
  __shared__ float4 h4[Hn / 8];       // 256 halves of h, fp16
  __shared__ int    ev_s[TP2n];
  __shared__ float  dt_s[TP2n];
  __shared__ float  pb[2][4];

  for (int i = tid; i < TP2n; i += 896) {
    ev_s[i] = event[b * TP2n + i];
    dt_s[i] = dtime[b * TP2n + i];
  }
  if (tid < Hn) { c_s[tid] = 0.f; cb_s[tid] = 0.f; }
  if (tid < Hn / 8) h4[tid] = make_float4(0.f, 0.f, 0.f, 0.f);

  const uint2* wtt = wt + (size_t)tid * 128;
  float acc_ll = 0.f;
  __syncthreads();

  for (int t = 0; t < Tn; ++t) {
    // ---- Phase A: z rows 2*tid, 2*tid+1 ----
    const int e = ev_s[t];
    float2 ew = *reinterpret_cast<const float2*>(EW + e * H7n + 2 * tid);
    float a0 = ew.x, a1 = ew.y;
#pragma unroll
    for (int k8 = 0; k8 < 32; ++k8) {
      float4 hq = h4[k8];
      uint2 w;
      f16x2 hh;
      hh = __builtin_bit_cast(f16x2, hq.x);
      w = wtt[4 * k8 + 0];
      a0 = fdot2f(__builtin_bit_cast(f16x2, w.x), hh, a0);
      a1 = fdot2f(__builtin_bit_cast(f16x2, w.y), hh, a1);
      hh = __builtin_bit_cast(f16x2, hq.y);
      w = wtt[4 * k8 + 1];
      a0 = fdot2f(__builtin_bit_cast(f16x2, w.x), hh, a0);
      a1 = fdot2f(__builtin_bit_cast(f16x2, w.y), hh, a1);
      hh = __builtin_bit_cast(f16x2, hq.z);
      w = wtt[4 * k8 + 2];
      a0 = fdot2f(__builtin_bit_cast(f16x2, w.x), hh, a0);
      a1 = fdot2f(__builtin_bit_cast(f16x2, w.y), hh, a1);
      hh = __builtin_bit_cast(f16x2, hq.w);
      w = wtt[4 * k8 + 3];
      a0 = fdot2f(__builtin_bit_cast(f16x2, w.x), hh, a0);
      a1 = fdot2f(__builtin_bit_cast(f16x2, w.y), hh, a1);
    }
    *reinterpret_cast<float2*>(&zbuf[2 * tid]) = make_float2(a0, a1);
    __syncthreads();

    // ---- Phase B: elementwise recurrence (threads 0..255) ----
    if (tid < Hn) {
      const int j = tid;
      float gi  = sigmf(zbuf[j]);
      float gf  = sigmf(zbuf[Hn + j]);
      float go  = sigmf(zbuf[2 * Hn + j]);
      float zc  = tanhfast(zbuf[3 * Hn + j]);
      float gib = sigmf(zbuf[4 * Hn + j]);
      float gfb = sigmf(zbuf[5 * Hn + j]);
      float gd  = softplusf(zbuf[6 * Hn + j]);
      float dt  = dt_s[t + 1];
      float ci  = gf * c_s[j] + gi * zc;
      float cbi = gfb * cb_s[j] + gib * zc;
      float cn  = cbi + (ci - cbi) * __expf(-gd * dt);
      float hn  = go * tanhfast(cn);
      c_s[j] = cn;
      cb_s[j] = cbi;
      reinterpret_cast<__half*>(h4)[j] = __float2half(hn);
      size_t row = ((size_t)b * Tn + t) * Hn + j;
      oc[row]  = __float2half(ci);
      ocb[row] = __float2half(cbi);
      ogd[row] = __float2half(gd);
      ogo[row] = __float2half(go);
      // target-row log-lambda partial
      int tgt = ev_s[t + 1];
      float p = (tgt < Kn) ? hn * Wl[tgt * Hn + j] : 0.f;
#pragma unroll
      for (int off = 32; off; off >>= 1) p += __shfl_down(p, off);
      if ((tid & 63) == 0) pb[t & 1][tid >> 6] = p;
      if (tid == 0 && t > 0) {
        int tp = ev_s[t];  // target of step t-1
        if (tp < Kn) {
          const float* q = pb[(t - 1) & 1];
          float d = q[0] + q[1] + q[2] + q[3];
          acc_ll += __logf(softplusf(d) + EPSF);
        }
      }
    }
    __syncthreads();
  }
  if (tid == 0) {
    int tl = ev_s[Tn];
    float v = acc_ll;
    if (tl < Kn) {
      const float* q = pb[(Tn - 1) & 1];
      float d = q[0] + q[1] + q[2] + q[3];
      v += __logf(softplusf(d) + EPSF);
    }
    loglik_sum[b] = v;
  }
}

// ---------------------------------------------------------------------------
// Sampling: 512 blocks (8 per batch) x 128 threads; thread k holds Wl row k
// in registers (fp16 pairs). Per sample: gather state, hy in LDS, 128 dots.
__global__ __launch_bounds__(128) void k_samp(
    const __half* __restrict__ oc, const __half* __restrict__ ocb,
    const __half* __restrict__ ogd, const __half* __restrict__ ogo,
    const float* __restrict__ Wl, const int* __restrict__ sidx,
    const float* __restrict__ sdt, const float* __restrict__ smask,
    float* __restrict__ lam_acc, float* __restrict__ mask_acc) {
  const int blk = blockIdx.x;
  const int b = blk >> 3;
  const int s0 = (blk & 7) * 128;
  const int tid = threadIdx.x;

  f16x2 wr[128];
  {
    const float* wrow = Wl + tid * Hn;
#pragma unroll
    for (int i = 0; i < 128; ++i) {
      f16x2 v; v[0] = (_Float16)wrow[2 * i]; v[1] = (_Float16)wrow[2 * i + 1];
      wr[i] = v;
    }
  }
  __shared__ float4 hy[Hn / 8];
  __shared__ float  red[2];
  float accl = 0.f, accm = 0.f;

  for (int s = 0; s < 128; ++s) {
    const int sg = (b << 10) + s0 + s;
    const int row = sidx[sg];
    const float dt = sdt[sg];
    __half* hh = reinterpret_cast<__half*>(hy);
#pragma unroll
    for (int u = 0; u < 2; ++u) {
      int i = tid + (u << 7);
      size_t off = (size_t)row * Hn + i;
      float c  = __half2float(oc[off]);
      float cb = __half2float(ocb[off]);
      float gd = __half2float(ogd[off]);
      float go = __half2float(ogo[off]);
      float cs = cb + (c - cb) * __expf(-gd * dt);
      hh[i] = __float2half(go * tanhfast(cs));
    }
    __syncthreads();
    float d = 0.f;
#pragma unroll
    for (int q = 0; q < 32; ++q) {
      float4 hq = hy[q];
      d = fdot2f(wr[4 * q + 0], __builtin_bit_cast(f16x2, hq.x), d);
      d = fdot2f(wr[4 * q + 1], __builtin_bit_cast(f16x2, hq.y), d);
      d = fdot2f(wr[4 * q + 2], __builtin_bit_cast(f16x2, hq.z), d);
      d = fdot2f(wr[4 * q + 3], __builtin_bit_cast(f16x2, hq.w), d);
    }
    float lam = softplusf(d);
#pragma unroll
    for (int off = 32; off; off >>= 1) lam += __shfl_down(lam, off);
    if ((tid & 63) == 0) red[tid >> 6] = lam;
    __syncthreads();
    if (tid == 0) {
      float m = smask[sg];
      accl += (red[0] + red[1]) * m;
      accm += m;
    }
  }
  if (tid == 0) {
    atomicAdd(&lam_acc[b], accl);
    atomicAdd(&mask_acc[b], accm);
  }
}

// ---------------------------------------------------------------------------
__global__ void k_final(const float* __restrict__ loglik_sum,
                        const float* __restrict__ lam_acc,
                        const float* __restrict__ mask_acc,
                        const float* __restrict__ duration,
                        float* __restrict__ out) {
  int b = threadIdx.x;
  if (b < Bn) out[b] = loglik_sum[b] - (lam_acc[b] / mask_acc[b]) * duration[b];
}

// ---------------------------------------------------------------------------
extern "C" void kernel_launch(void* const* d_in, const int* in_sizes, int n_in,
                              void* d_out, int out_size, void* d_ws, size_t ws_size,
                              hipStream_t stream) {
  const int*   event    = (const int*)d_in[0];
  const float* dtime    = (const float*)d_in[1];
  // d_in[2] = post (unused by reference)
  const float* duration = (const float*)d_in[3];
  const float* sdt      = (const float*)d_in[4];
  const int*   sidx     = (const int*)d_in[5];
  const float* smask    = (const float*)d_in[6];
  const float* Emb      = (const float*)d_in[7];
  const float* W        = (const float*)d_in[8];
  const float* bv       = (const float*)d_in[9];
  const float* Wl       = (const float*)d_in[10];

  char* ws = (char*)d_ws;
  // layout: EW(0.94MB) @0 | wt(0.92MB) @1MB | accums @2MB | fp16 state @4MB
  float*  EW         = (float*)(ws + 0);
  uint2*  wt         = (uint2*)(ws + (1u << 20));
  float*  lam_acc    = (float*)(ws + (2u << 20));
  float*  mask_acc   = lam_acc + 64;
  float*  loglik_sum = lam_acc + 128;
  __half* oc         = (__half*)(ws + (4u << 20));
  const size_t asz = (size_t)Bn * Tn * Hn;  // 16,760,832 elems (fp16)
  __half* ocb = oc + asz;
  __half* ogd = ocb + asz;
  __half* ogo = ogd + asz;
  // total workspace required: 4MB + 4*asz*2B ~= 139 MB

  k_ew<<<dim3(NEn), dim3(256), 0, stream>>>(Emb, W, bv, EW);
  k_wt<<<dim3((896 * 128 + 255) / 256), dim3(256), 0, stream>>>(W, wt);
  k_init<<<dim3(1), dim3(64), 0, stream>>>(lam_acc, mask_acc);
  k_scan<<<dim3(Bn), dim3(896), 0, stream>>>(event, dtime, EW, wt, Wl,
                                             oc, ocb, ogd, ogo, loglik_sum);
  k_samp<<<dim3(512), dim3(128), 0, stream>>>(oc, ocb, ogd, ogo, Wl, sidx,
                                              sdt, smask, lam_acc, mask_acc);
  k_final<<<dim3(1), dim3(64), 0, stream>>>(loglik_sum, lam_acc, mask_acc,
                                            duration, (float*)d_out);
}